// Round 6
// baseline (60.053 us; speedup 1.0000x reference)
//
#include <hip/hip_runtime.h>
#include <hip/hip_bf16.h>
#include <math.h>

#define NBATCH 8
#define NUM    4096
#define CDIM   1024
#define KP     16        // prototype columns
#define KC     17        // cost columns incl. trash
#define KSTR   20        // padded row stride for K in ws
#define NITER  100
#define NSTEP  32        // K-steps of 32 c each (32*32 = 1024)
#define FEPS   1e-12f
#define FEPS2  4.096e-9f // FEPS * 4096 (col-folded eps for the v update)

typedef __attribute__((ext_vector_type(8))) short v8s;    // 8 bf16 (4 VGPR)
typedef __attribute__((ext_vector_type(4))) float v4f;    // MFMA acc
typedef __attribute__((ext_vector_type(2))) float f32x2;  // packed fp32 pair

// ws layout (float offsets)
#define WS_BHI 0                            // [8][32][64] v8s  (65536 float-slots)
#define WS_BLO 65536                        // [8][32][64] v8s
#define WS_K   131072                       // [8][4096][20] f32 K matrix
#define WS_NBG (WS_K + NBATCH*NUM*KSTR)     // [8] num_bg

// fp32 -> bf16 hi/lo split (hi + lo reconstructs v to ~2^-17 rel)
__device__ inline void f2hl(float v, unsigned short& h, unsigned short& l) {
  __hip_bfloat16 bh = __float2bfloat16(v);
  h = __builtin_bit_cast(unsigned short, bh);
  float hf = __uint_as_float(((unsigned int)h) << 16);
  __hip_bfloat16 bl = __float2bfloat16(v - hf);
  l = __builtin_bit_cast(unsigned short, bl);
}

// ---------------- kernel A: proto norms + num_bg + B-fragment build ----------------
// k-map (must match attk's A loads): k(l,j) = (l>>4)*4 + (j&3) + 16*(j>>2).
__global__ __launch_bounds__(256) void prep_kernel(
    const float* __restrict__ protos, const int* __restrict__ masks,
    float* __restrict__ ws) {
  int bb = blockIdx.x;
  int t = threadIdx.x;
  int w = t >> 6, lane = t & 63;

  __shared__ float rnl[KP];
  __shared__ float red[4];

  // phase 1: per-proto 1/||p||  (wave w handles protos w, w+4, w+8, w+12)
  #pragma unroll
  for (int pi = 0; pi < 4; ++pi) {
    int p = w + 4 * pi;
    const float* src = protos + ((size_t)(bb * KP + p)) * CDIM + lane * 16;
    float ss = 0.f;
    #pragma unroll
    for (int q = 0; q < 4; ++q) {
      float4 v = *(const float4*)(src + 4 * q);
      ss += v.x * v.x + v.y * v.y + v.z * v.z + v.w * v.w;
    }
    #pragma unroll
    for (int m = 1; m < 64; m <<= 1) ss += __shfl_xor(ss, m, 64);
    if (lane == 0) rnl[p] = 1.0f / fmaxf(sqrtf(ss), FEPS);
  }

  // num_bg = count(masks == 0)
  int cnt = 0;
  for (int i = t; i < NUM; i += 256) cnt += (masks[bb * NUM + i] == 0);
  float c = (float)cnt;
  #pragma unroll
  for (int m = 1; m < 64; m <<= 1) c += __shfl_xor(c, m, 64);
  if (lane == 0) red[w] = c;
  __syncthreads();
  if (t == 0) ws[WS_NBG + bb] = red[0] + red[1] + red[2] + red[3];

  // phase 2: build B-frags. slot (s, l): proto p = l&15, c-base = 32s + (l>>4)*4
  typedef __attribute__((ext_vector_type(8))) unsigned short v8u;
  v8u* Bhi = (v8u*)(ws + WS_BHI);
  v8u* Blo = (v8u*)(ws + WS_BLO);
  for (int idx = t; idx < NSTEP * 64; idx += 256) {
    int s = idx >> 6, l = idx & 63;
    int p = l & 15, q4 = (l >> 4) * 4;
    float rp = rnl[p];
    const float* src = protos + ((size_t)(bb * KP + p)) * CDIM + 32 * s + q4;
    float4 va = *(const float4*)(src);        // j = 0..3  (k = q4+0..3)
    float4 vb = *(const float4*)(src + 16);   // j = 4..7  (k = 16+q4+0..3)
    float vals[8] = { va.x * rp, va.y * rp, va.z * rp, va.w * rp,
                      vb.x * rp, vb.y * rp, vb.z * rp, vb.w * rp };
    v8u hv, lv;
    #pragma unroll
    for (int j = 0; j < 8; ++j) {
      unsigned short h, lo2;
      f2hl(vals[j], h, lo2);
      hv[j] = h; lv[j] = lo2;
    }
    int slot = (bb * NSTEP + s) * 64 + l;
    Bhi[slot] = hv;
    Blo[slot] = lv;
  }
}

// ---------------- kernel B: att + K build via MFMA ----------------
// grid (128, 8), block 128 = 2 waves; each wave owns a 16-row tile.
// Round-5 ran this shape at 2 waves/SIMD (512 blocks of 4 waves) and was
// HBM-latency-bound at ~47 us (2.2x the 21 us feat-read floor). This round:
// 1024 blocks x 2 waves -> 16 waves/CU (4/SIMD), unroll-4 load pipeline,
// and a split accumulator to break the serial MFMA dependency chain.
__global__ __launch_bounds__(128, 4) void attk_kernel(
    const float* __restrict__ feat, const int* __restrict__ masks,
    const float* __restrict__ ws, float* __restrict__ Kmat) {
  int bb = blockIdx.y;
  int w = threadIdx.x >> 6, lane = threadIdx.x & 63;
  int n0 = blockIdx.x * 32 + w * 16;
  int rowa = lane & 15;          // A-frag row / B-frag col(proto)
  int quad = lane >> 4;          // k-chunk selector

  const v8s* Bhi = (const v8s*)(ws + WS_BHI) + (size_t)bb * NSTEP * 64 + lane;
  const v8s* Blo = (const v8s*)(ws + WS_BLO) + (size_t)bb * NSTEP * 64 + lane;
  const float* frow = feat + ((size_t)(bb * NUM + n0 + rowa)) * CDIM + quad * 4;

  v4f acc0 = {0.f, 0.f, 0.f, 0.f};
  v4f acc1 = {0.f, 0.f, 0.f, 0.f};
  float ss0 = 0.f, ss1 = 0.f;

  #pragma unroll 4
  for (int s = 0; s < NSTEP; ++s) {
    float4 va = *(const float4*)(frow + 32 * s);        // k = quad*4 + 0..3
    float4 vb = *(const float4*)(frow + 32 * s + 16);   // k = 16 + quad*4 + 0..3
    v8s bh = Bhi[s * 64];
    v8s bl = Blo[s * 64];
    float vals[8] = { va.x, va.y, va.z, va.w, vb.x, vb.y, vb.z, vb.w };
    v8s ah, al;
    #pragma unroll
    for (int j = 0; j < 8; ++j) {
      unsigned short h, lo2;
      f2hl(vals[j], h, lo2);
      ah[j] = (short)h; al[j] = (short)lo2;
      if (j & 1) ss1 = fmaf(vals[j], vals[j], ss1);
      else       ss0 = fmaf(vals[j], vals[j], ss0);
    }
    if (s & 1) {
      acc1 = __builtin_amdgcn_mfma_f32_16x16x32_bf16(ah, bh, acc1, 0, 0, 0);
      acc1 = __builtin_amdgcn_mfma_f32_16x16x32_bf16(al, bh, acc1, 0, 0, 0);
      acc1 = __builtin_amdgcn_mfma_f32_16x16x32_bf16(ah, bl, acc1, 0, 0, 0);
    } else {
      acc0 = __builtin_amdgcn_mfma_f32_16x16x32_bf16(ah, bh, acc0, 0, 0, 0);
      acc0 = __builtin_amdgcn_mfma_f32_16x16x32_bf16(al, bh, acc0, 0, 0, 0);
      acc0 = __builtin_amdgcn_mfma_f32_16x16x32_bf16(ah, bl, acc0, 0, 0, 0);
    }
  }
  v4f acc = acc0 + acc1;
  float ss = ss0 + ss1;

  // full row norm for row (lane&15): lanes l, l^16, l^32, l^48 hold disjoint quarters
  ss += __shfl_xor(ss, 16, 64);
  ss += __shfl_xor(ss, 32, 64);
  float rn = 1.0f / fmaxf(sqrtf(ss), FEPS);

  // C/D layout (m89-verified): col = lane&15 (proto), row = quad*4 + q
  float* Kb = Kmat + (size_t)bb * NUM * KSTR;
  #pragma unroll
  for (int q = 0; q < 4; ++q) {
    int r = quad * 4 + q;
    float rq = __shfl(rn, r, 64);           // lane r (<16) holds row r's norm
    float kv = __expf((acc[q] * rq - 1.0f) * 20.0f);   // exp(-(1-att)/0.05)
    Kb[(size_t)(n0 + r) * KSTR + rowa] = kv;
  }
  if (lane < 16) {
    int mv = masks[bb * NUM + n0 + lane];
    // exp(-2/0.05) = exp(-40), or exp(0)=1
    Kb[(size_t)(n0 + lane) * KSTR + 16] = (mv > 0) ? 4.248354255291589e-18f : 1.0f;
  }
}

// ---------------- kernel C: Sinkhorn iterations + epilogue ----------------
// 8 blocks (one per batch) x 512 threads; thread owns rows t + 512*j.
// Inner loops packed as f32x2 + elementwise_fma -> v_pk_fma_f32 (halves VALU
// issue of the 2x(8x17) FMA core). col = 1/4096 is folded out exactly:
// u' = 1/max(Kv,eps); v = (row*4096)/max(K^T u', eps*4096); epilogue u*4096 = u'.
__global__ __launch_bounds__(512, 2) void sinkhorn_kernel(
    const float* __restrict__ Kmat, const float* __restrict__ numbg,
    float* __restrict__ out) {
  int bb = blockIdx.x;
  int t = threadIdx.x;
  const float* Kb = Kmat + (size_t)bb * NUM * KSTR;

  f32x2 kreg2[8][8];
  float k16[8];
  #pragma unroll
  for (int j = 0; j < 8; ++j) {
    int n = t + 512 * j;
    const float* kr = Kb + (size_t)n * KSTR;
    #pragma unroll
    for (int q = 0; q < 4; ++q) {
      float4 v = *(const float4*)(kr + 4 * q);
      kreg2[j][2*q+0] = f32x2{v.x, v.y};
      kreg2[j][2*q+1] = f32x2{v.z, v.w};
    }
    k16[j] = kr[16];
  }

  float nbg    = numbg[bb];
  // col-folded row constants (x4096)
  float rowp_c  = (4096.0f - nbg) * (1.0f / 16.0f);
  float row16_c = nbg;

  __shared__ float vlds[KC];
  __shared__ float part[KC][520];
  __shared__ int   flags[2];
  if (t < KC) vlds[t] = 1.0f;
  if (t == 0) { flags[0] = 0; flags[1] = 0; }
  __syncthreads();

  float u[8];
  #pragma unroll 1
  for (int it = 0; it < NITER; ++it) {
    f32x2 vr2[8];
    #pragma unroll
    for (int p = 0; p < 8; ++p) vr2[p] = f32x2{vlds[2*p], vlds[2*p+1]};
    float vr16 = vlds[16];

    f32x2 s2[8];
    #pragma unroll
    for (int p = 0; p < 8; ++p) s2[p] = f32x2{0.f, 0.f};
    float s16 = 0.f;

    #pragma unroll
    for (int j = 0; j < 8; ++j) {
      f32x2 d2 = kreg2[j][0] * vr2[0];
      #pragma unroll
      for (int p = 1; p < 8; ++p)
        d2 = __builtin_elementwise_fma(kreg2[j][p], vr2[p], d2);
      float dot = d2.x + d2.y + k16[j] * vr16;
      float uu = __builtin_amdgcn_rcpf(fmaxf(dot, FEPS));   // u' = 1/dot
      u[j] = uu;
      f32x2 uu2 = f32x2{uu, uu};
      #pragma unroll
      for (int p = 0; p < 8; ++p)
        s2[p] = __builtin_elementwise_fma(kreg2[j][p], uu2, s2[p]);
      s16 = fmaf(k16[j], uu, s16);
    }
    #pragma unroll
    for (int p = 0; p < 8; ++p) {
      part[2*p+0][t] = s2[p].x;
      part[2*p+1][t] = s2[p].y;
    }
    part[16][t] = s16;
    if (t == 0) flags[it & 1] = 0;
    __syncthreads();
    // stage 2: 17 groups x 16 threads sum 512 partials each
    if (t < 272) {
      int k = t >> 4, i = t & 15;
      float acc = 0.f;
      #pragma unroll
      for (int j = 0; j < 32; ++j) acc += part[k][i + 16 * j];
      acc += __shfl_xor(acc, 1, 64);
      acc += __shfl_xor(acc, 2, 64);
      acc += __shfl_xor(acc, 4, 64);
      acc += __shfl_xor(acc, 8, 64);
      if (i == 0) {
        float rw = (k < KP) ? rowp_c : row16_c;
        float vold = vlds[k];
        float vnew = rw * __builtin_amdgcn_rcpf(fmaxf(acc, FEPS2));
        vlds[k] = vnew;
        if (fabsf(vnew - vold) > 1e-6f * fabsf(vnew)) flags[it & 1] = 1;
      }
    }
    __syncthreads();
    if (flags[it & 1] == 0) break;   // converged: remaining ref iters are no-ops
  }

  // epilogue: T = u * K * v * 4096, relu, drop trash col; u[]*4096*col == u[]
  float vl[KP];
  #pragma unroll
  for (int p = 0; p < KP; ++p) vl[p] = vlds[p];
  float* ob = out + (size_t)bb * NUM * KP;
  #pragma unroll
  for (int j = 0; j < 8; ++j) {
    int n = t + 512 * j;
    float uu = u[j];
    float* dst = ob + (size_t)n * KP;
    #pragma unroll
    for (int q = 0; q < 4; ++q) {
      float4 v;
      v.x = fmaxf(uu * kreg2[j][2*q+0].x * vl[4*q+0], 0.f);
      v.y = fmaxf(uu * kreg2[j][2*q+0].y * vl[4*q+1], 0.f);
      v.z = fmaxf(uu * kreg2[j][2*q+1].x * vl[4*q+2], 0.f);
      v.w = fmaxf(uu * kreg2[j][2*q+1].y * vl[4*q+3], 0.f);
      *(float4*)(dst + 4 * q) = v;
    }
  }
}

extern "C" void kernel_launch(void* const* d_in, const int* in_sizes, int n_in,
                              void* d_out, int out_size, void* d_ws, size_t ws_size,
                              hipStream_t stream) {
  const float* feat   = (const float*)d_in[0];
  const float* protos = (const float*)d_in[1];
  const int*   masks  = (const int*)d_in[2];
  float* out = (float*)d_out;
  float* ws  = (float*)d_ws;

  float* Kmat  = ws + WS_K;
  float* numbg = ws + WS_NBG;

  hipLaunchKernelGGL(prep_kernel, dim3(NBATCH), dim3(256), 0, stream,
                     protos, masks, ws);
  hipLaunchKernelGGL(attk_kernel, dim3(128, NBATCH), dim3(128), 0, stream,
                     feat, masks, ws, Kmat);
  hipLaunchKernelGGL(sinkhorn_kernel, dim3(NBATCH), dim3(512), 0, stream,
                     Kmat, numbg, out);
}

// Round 7
// 58.269 us; speedup vs baseline: 1.0306x; 1.0306x over previous
//
#include <hip/hip_runtime.h>
#include <hip/hip_bf16.h>
#include <math.h>

#define NBATCH 8
#define NUM    4096
#define CDIM   1024
#define KP     16        // prototype columns
#define KC     17        // cost columns incl. trash
#define KSTR   20        // padded row stride for K in ws
#define NITER  100
#define NSTEP  32        // K-steps of 32 c each (32*32 = 1024)
#define FEPS   1e-12f
#define FEPS2  4.096e-9f // FEPS * 4096 (col-folded eps for the v update)

typedef __attribute__((ext_vector_type(8))) short v8s;    // 8 bf16 (4 VGPR)
typedef __attribute__((ext_vector_type(4))) float v4f;    // MFMA acc
typedef __attribute__((ext_vector_type(2))) float f32x2;  // packed fp32 pair

// ws layout (float offsets)
#define WS_BHI 0                            // [8][32][64] v8s  (65536 float-slots)
#define WS_BLO 65536                        // [8][32][64] v8s
#define WS_K   131072                       // [8][4096][20] f32 K matrix
#define WS_NBG (WS_K + NBATCH*NUM*KSTR)     // [8] num_bg

// fp32 -> bf16 hi/lo split (hi + lo reconstructs v to ~2^-17 rel)
__device__ inline void f2hl(float v, unsigned short& h, unsigned short& l) {
  __hip_bfloat16 bh = __float2bfloat16(v);
  h = __builtin_bit_cast(unsigned short, bh);
  float hf = __uint_as_float(((unsigned int)h) << 16);
  __hip_bfloat16 bl = __float2bfloat16(v - hf);
  l = __builtin_bit_cast(unsigned short, bl);
}

// ---------------- kernel A: proto norms + num_bg + B-fragment build ----------------
// k-map (must match attk's A loads): k(l,j) = (l>>4)*4 + (j&3) + 16*(j>>2).
__global__ __launch_bounds__(256) void prep_kernel(
    const float* __restrict__ protos, const int* __restrict__ masks,
    float* __restrict__ ws) {
  int bb = blockIdx.x;
  int t = threadIdx.x;
  int w = t >> 6, lane = t & 63;

  __shared__ float rnl[KP];
  __shared__ float red[4];

  // phase 1: per-proto 1/||p||  (wave w handles protos w, w+4, w+8, w+12)
  #pragma unroll
  for (int pi = 0; pi < 4; ++pi) {
    int p = w + 4 * pi;
    const float* src = protos + ((size_t)(bb * KP + p)) * CDIM + lane * 16;
    float ss = 0.f;
    #pragma unroll
    for (int q = 0; q < 4; ++q) {
      float4 v = *(const float4*)(src + 4 * q);
      ss += v.x * v.x + v.y * v.y + v.z * v.z + v.w * v.w;
    }
    #pragma unroll
    for (int m = 1; m < 64; m <<= 1) ss += __shfl_xor(ss, m, 64);
    if (lane == 0) rnl[p] = 1.0f / fmaxf(sqrtf(ss), FEPS);
  }

  // num_bg = count(masks == 0)
  int cnt = 0;
  for (int i = t; i < NUM; i += 256) cnt += (masks[bb * NUM + i] == 0);
  float c = (float)cnt;
  #pragma unroll
  for (int m = 1; m < 64; m <<= 1) c += __shfl_xor(c, m, 64);
  if (lane == 0) red[w] = c;
  __syncthreads();
  if (t == 0) ws[WS_NBG + bb] = red[0] + red[1] + red[2] + red[3];

  // phase 2: build B-frags. slot (s, l): proto p = l&15, c-base = 32s + (l>>4)*4
  typedef __attribute__((ext_vector_type(8))) unsigned short v8u;
  v8u* Bhi = (v8u*)(ws + WS_BHI);
  v8u* Blo = (v8u*)(ws + WS_BLO);
  for (int idx = t; idx < NSTEP * 64; idx += 256) {
    int s = idx >> 6, l = idx & 63;
    int p = l & 15, q4 = (l >> 4) * 4;
    float rp = rnl[p];
    const float* src = protos + ((size_t)(bb * KP + p)) * CDIM + 32 * s + q4;
    float4 va = *(const float4*)(src);        // j = 0..3  (k = q4+0..3)
    float4 vb = *(const float4*)(src + 16);   // j = 4..7  (k = 16+q4+0..3)
    float vals[8] = { va.x * rp, va.y * rp, va.z * rp, va.w * rp,
                      vb.x * rp, vb.y * rp, vb.z * rp, vb.w * rp };
    v8u hv, lv;
    #pragma unroll
    for (int j = 0; j < 8; ++j) {
      unsigned short h, lo2;
      f2hl(vals[j], h, lo2);
      hv[j] = h; lv[j] = lo2;
    }
    int slot = (bb * NSTEP + s) * 64 + l;
    Bhi[slot] = hv;
    Blo[slot] = lv;
  }
}

// ---------------- kernel B: att + K build via MFMA ----------------
// grid (64, 8), block 256 = 4 waves; each wave owns a 16-row tile.
// launch_bounds(256, 2): rounds 5/6 used min-waves=4 (128-VGPR cap) and the
// inner loop (2 accs + 4 in-flight loads + f2hl temps) spilled to scratch —
// unroll-4 under that cap REGRESSED (round 6). 256-VGPR budget -> no spill;
// occupancy stays grid-limited at 2 blocks/CU (8 waves/CU).
__global__ __launch_bounds__(256, 2) void attk_kernel(
    const float* __restrict__ feat, const int* __restrict__ masks,
    const float* __restrict__ ws, float* __restrict__ Kmat) {
  int bb = blockIdx.y;
  int w = threadIdx.x >> 6, lane = threadIdx.x & 63;
  int n0 = blockIdx.x * 64 + w * 16;
  int rowa = lane & 15;          // A-frag row / B-frag col(proto)
  int quad = lane >> 4;          // k-chunk selector

  const v8s* Bhi = (const v8s*)(ws + WS_BHI) + (size_t)bb * NSTEP * 64 + lane;
  const v8s* Blo = (const v8s*)(ws + WS_BLO) + (size_t)bb * NSTEP * 64 + lane;
  const float* frow = feat + ((size_t)(bb * NUM + n0 + rowa)) * CDIM + quad * 4;

  v4f acc0 = {0.f, 0.f, 0.f, 0.f};
  v4f acc1 = {0.f, 0.f, 0.f, 0.f};
  float ss0 = 0.f, ss1 = 0.f;

  #pragma unroll 2
  for (int s = 0; s < NSTEP; ++s) {
    float4 va = *(const float4*)(frow + 32 * s);        // k = quad*4 + 0..3
    float4 vb = *(const float4*)(frow + 32 * s + 16);   // k = 16 + quad*4 + 0..3
    v8s bh = Bhi[s * 64];
    v8s bl = Blo[s * 64];
    float vals[8] = { va.x, va.y, va.z, va.w, vb.x, vb.y, vb.z, vb.w };
    v8s ah, al;
    #pragma unroll
    for (int j = 0; j < 8; ++j) {
      unsigned short h, lo2;
      f2hl(vals[j], h, lo2);
      ah[j] = (short)h; al[j] = (short)lo2;
      if (j & 1) ss1 = fmaf(vals[j], vals[j], ss1);
      else       ss0 = fmaf(vals[j], vals[j], ss0);
    }
    if (s & 1) {
      acc1 = __builtin_amdgcn_mfma_f32_16x16x32_bf16(ah, bh, acc1, 0, 0, 0);
      acc1 = __builtin_amdgcn_mfma_f32_16x16x32_bf16(al, bh, acc1, 0, 0, 0);
      acc1 = __builtin_amdgcn_mfma_f32_16x16x32_bf16(ah, bl, acc1, 0, 0, 0);
    } else {
      acc0 = __builtin_amdgcn_mfma_f32_16x16x32_bf16(ah, bh, acc0, 0, 0, 0);
      acc0 = __builtin_amdgcn_mfma_f32_16x16x32_bf16(al, bh, acc0, 0, 0, 0);
      acc0 = __builtin_amdgcn_mfma_f32_16x16x32_bf16(ah, bl, acc0, 0, 0, 0);
    }
  }
  v4f acc = acc0 + acc1;
  float ss = ss0 + ss1;

  // full row norm for row (lane&15): lanes l, l^16, l^32, l^48 hold disjoint quarters
  ss += __shfl_xor(ss, 16, 64);
  ss += __shfl_xor(ss, 32, 64);
  float rn = 1.0f / fmaxf(sqrtf(ss), FEPS);

  // C/D layout (m89-verified): col = lane&15 (proto), row = quad*4 + q
  float* Kb = Kmat + (size_t)bb * NUM * KSTR;
  #pragma unroll
  for (int q = 0; q < 4; ++q) {
    int r = quad * 4 + q;
    float rq = __shfl(rn, r, 64);           // lane r (<16) holds row r's norm
    float kv = __expf((acc[q] * rq - 1.0f) * 20.0f);   // exp(-(1-att)/0.05)
    Kb[(size_t)(n0 + r) * KSTR + rowa] = kv;
  }
  if (lane < 16) {
    int mv = masks[bb * NUM + n0 + lane];
    // exp(-2/0.05) = exp(-40), or exp(0)=1
    Kb[(size_t)(n0 + lane) * KSTR + 16] = (mv > 0) ? 4.248354255291589e-18f : 1.0f;
  }
}

// ---------------- kernel C: Sinkhorn iterations + epilogue ----------------
// 8 blocks (one per batch) x 512 threads; thread owns rows t + 512*j.
// Inner loops packed as f32x2 + elementwise_fma -> v_pk_fma_f32. col = 1/4096
// folded out exactly: u' = 1/max(Kv,eps); v = (row*4096)/max(K^T u', eps*4096).
__global__ __launch_bounds__(512, 2) void sinkhorn_kernel(
    const float* __restrict__ Kmat, const float* __restrict__ numbg,
    float* __restrict__ out) {
  int bb = blockIdx.x;
  int t = threadIdx.x;
  const float* Kb = Kmat + (size_t)bb * NUM * KSTR;

  f32x2 kreg2[8][8];
  float k16[8];
  #pragma unroll
  for (int j = 0; j < 8; ++j) {
    int n = t + 512 * j;
    const float* kr = Kb + (size_t)n * KSTR;
    #pragma unroll
    for (int q = 0; q < 4; ++q) {
      float4 v = *(const float4*)(kr + 4 * q);
      kreg2[j][2*q+0] = f32x2{v.x, v.y};
      kreg2[j][2*q+1] = f32x2{v.z, v.w};
    }
    k16[j] = kr[16];
  }

  float nbg    = numbg[bb];
  // col-folded row constants (x4096)
  float rowp_c  = (4096.0f - nbg) * (1.0f / 16.0f);
  float row16_c = nbg;

  __shared__ float vlds[KC];
  __shared__ float part[KC][520];
  __shared__ int   flags[2];
  if (t < KC) vlds[t] = 1.0f;
  if (t == 0) { flags[0] = 0; flags[1] = 0; }
  __syncthreads();

  float u[8];
  #pragma unroll 1
  for (int it = 0; it < NITER; ++it) {
    f32x2 vr2[8];
    #pragma unroll
    for (int p = 0; p < 8; ++p) vr2[p] = f32x2{vlds[2*p], vlds[2*p+1]};
    float vr16 = vlds[16];

    f32x2 s2[8];
    #pragma unroll
    for (int p = 0; p < 8; ++p) s2[p] = f32x2{0.f, 0.f};
    float s16 = 0.f;

    #pragma unroll
    for (int j = 0; j < 8; ++j) {
      f32x2 d2 = kreg2[j][0] * vr2[0];
      #pragma unroll
      for (int p = 1; p < 8; ++p)
        d2 = __builtin_elementwise_fma(kreg2[j][p], vr2[p], d2);
      float dot = d2.x + d2.y + k16[j] * vr16;
      float uu = __builtin_amdgcn_rcpf(fmaxf(dot, FEPS));   // u' = 1/dot
      u[j] = uu;
      f32x2 uu2 = f32x2{uu, uu};
      #pragma unroll
      for (int p = 0; p < 8; ++p)
        s2[p] = __builtin_elementwise_fma(kreg2[j][p], uu2, s2[p]);
      s16 = fmaf(k16[j], uu, s16);
    }
    #pragma unroll
    for (int p = 0; p < 8; ++p) {
      part[2*p+0][t] = s2[p].x;
      part[2*p+1][t] = s2[p].y;
    }
    part[16][t] = s16;
    if (t == 0) flags[it & 1] = 0;
    __syncthreads();
    // stage 2: 17 groups x 16 threads sum 512 partials each
    if (t < 272) {
      int k = t >> 4, i = t & 15;
      float acc = 0.f;
      #pragma unroll
      for (int j = 0; j < 32; ++j) acc += part[k][i + 16 * j];
      acc += __shfl_xor(acc, 1, 64);
      acc += __shfl_xor(acc, 2, 64);
      acc += __shfl_xor(acc, 4, 64);
      acc += __shfl_xor(acc, 8, 64);
      if (i == 0) {
        float rw = (k < KP) ? rowp_c : row16_c;
        float vold = vlds[k];
        float vnew = rw * __builtin_amdgcn_rcpf(fmaxf(acc, FEPS2));
        vlds[k] = vnew;
        if (fabsf(vnew - vold) > 1e-6f * fabsf(vnew)) flags[it & 1] = 1;
      }
    }
    __syncthreads();
    if (flags[it & 1] == 0) break;   // converged: remaining ref iters are no-ops
  }

  // epilogue: T = u * K * v * 4096, relu, drop trash col; u[]*4096*col == u[]
  float vl[KP];
  #pragma unroll
  for (int p = 0; p < KP; ++p) vl[p] = vlds[p];
  float* ob = out + (size_t)bb * NUM * KP;
  #pragma unroll
  for (int j = 0; j < 8; ++j) {
    int n = t + 512 * j;
    float uu = u[j];
    float* dst = ob + (size_t)n * KP;
    #pragma unroll
    for (int q = 0; q < 4; ++q) {
      float4 v;
      v.x = fmaxf(uu * kreg2[j][2*q+0].x * vl[4*q+0], 0.f);
      v.y = fmaxf(uu * kreg2[j][2*q+0].y * vl[4*q+1], 0.f);
      v.z = fmaxf(uu * kreg2[j][2*q+1].x * vl[4*q+2], 0.f);
      v.w = fmaxf(uu * kreg2[j][2*q+1].y * vl[4*q+3], 0.f);
      *(float4*)(dst + 4 * q) = v;
    }
  }
}

extern "C" void kernel_launch(void* const* d_in, const int* in_sizes, int n_in,
                              void* d_out, int out_size, void* d_ws, size_t ws_size,
                              hipStream_t stream) {
  const float* feat   = (const float*)d_in[0];
  const float* protos = (const float*)d_in[1];
  const int*   masks  = (const int*)d_in[2];
  float* out = (float*)d_out;
  float* ws  = (float*)d_ws;

  float* Kmat  = ws + WS_K;
  float* numbg = ws + WS_NBG;

  hipLaunchKernelGGL(prep_kernel, dim3(NBATCH), dim3(256), 0, stream,
                     protos, masks, ws);
  hipLaunchKernelGGL(attk_kernel, dim3(64, NBATCH), dim3(256), 0, stream,
                     feat, masks, ws, Kmat);
  hipLaunchKernelGGL(sinkhorn_kernel, dim3(NBATCH), dim3(512), 0, stream,
                     Kmat, numbg, out);
}

// Round 8
// 56.412 us; speedup vs baseline: 1.0645x; 1.0329x over previous
//
#include <hip/hip_runtime.h>
#include <hip/hip_bf16.h>
#include <math.h>

#define NBATCH 8
#define NUM    4096
#define CDIM   1024
#define KP     16        // prototype columns
#define KC     17        // cost columns incl. trash
#define KSTR   20        // padded row stride for K in ws
#define NITER  100
#define NSTEP  32        // K-steps of 32 c each (32*32 = 1024)
#define HSTEP  16        // steps per c-half
#define FEPS   1e-12f
#define FEPS2  4.096e-9f // FEPS * 4096 (col-folded eps for the v update)

typedef __attribute__((ext_vector_type(8))) short v8s;    // 8 bf16 (4 VGPR)
typedef __attribute__((ext_vector_type(4))) float v4f;    // MFMA acc
typedef __attribute__((ext_vector_type(2))) float f32x2;  // packed fp32 pair

// ws layout (float offsets)
#define WS_BHI 0                            // [8][32][64] v8s  (65536 float-slots)
#define WS_BLO 65536                        // [8][32][64] v8s
#define WS_K   131072                       // [8][4096][20] f32 K matrix
#define WS_NBG (WS_K + NBATCH*NUM*KSTR)     // [8] num_bg

// fp32 -> bf16 hi/lo split (hi + lo reconstructs v to ~2^-17 rel)
__device__ inline void f2hl(float v, unsigned short& h, unsigned short& l) {
  __hip_bfloat16 bh = __float2bfloat16(v);
  h = __builtin_bit_cast(unsigned short, bh);
  float hf = __uint_as_float(((unsigned int)h) << 16);
  __hip_bfloat16 bl = __float2bfloat16(v - hf);
  l = __builtin_bit_cast(unsigned short, bl);
}

// ---------------- kernel A: proto norms + num_bg + B-fragment build ----------------
// k-map (must match attk's A loads): k(l,j) = (l>>4)*4 + (j&3) + 16*(j>>2).
__global__ __launch_bounds__(256) void prep_kernel(
    const float* __restrict__ protos, const int* __restrict__ masks,
    float* __restrict__ ws) {
  int bb = blockIdx.x;
  int t = threadIdx.x;
  int w = t >> 6, lane = t & 63;

  __shared__ float rnl[KP];
  __shared__ float red[4];

  // phase 1: per-proto 1/||p||  (wave w handles protos w, w+4, w+8, w+12)
  #pragma unroll
  for (int pi = 0; pi < 4; ++pi) {
    int p = w + 4 * pi;
    const float* src = protos + ((size_t)(bb * KP + p)) * CDIM + lane * 16;
    float ss = 0.f;
    #pragma unroll
    for (int q = 0; q < 4; ++q) {
      float4 v = *(const float4*)(src + 4 * q);
      ss += v.x * v.x + v.y * v.y + v.z * v.z + v.w * v.w;
    }
    #pragma unroll
    for (int m = 1; m < 64; m <<= 1) ss += __shfl_xor(ss, m, 64);
    if (lane == 0) rnl[p] = 1.0f / fmaxf(sqrtf(ss), FEPS);
  }

  // num_bg = count(masks == 0)
  int cnt = 0;
  for (int i = t; i < NUM; i += 256) cnt += (masks[bb * NUM + i] == 0);
  float c = (float)cnt;
  #pragma unroll
  for (int m = 1; m < 64; m <<= 1) c += __shfl_xor(c, m, 64);
  if (lane == 0) red[w] = c;
  __syncthreads();
  if (t == 0) ws[WS_NBG + bb] = red[0] + red[1] + red[2] + red[3];

  // phase 2: build B-frags. slot (s, l): proto p = l&15, c-base = 32s + (l>>4)*4
  typedef __attribute__((ext_vector_type(8))) unsigned short v8u;
  v8u* Bhi = (v8u*)(ws + WS_BHI);
  v8u* Blo = (v8u*)(ws + WS_BLO);
  for (int idx = t; idx < NSTEP * 64; idx += 256) {
    int s = idx >> 6, l = idx & 63;
    int p = l & 15, q4 = (l >> 4) * 4;
    float rp = rnl[p];
    const float* src = protos + ((size_t)(bb * KP + p)) * CDIM + 32 * s + q4;
    float4 va = *(const float4*)(src);        // j = 0..3  (k = q4+0..3)
    float4 vb = *(const float4*)(src + 16);   // j = 4..7  (k = 16+q4+0..3)
    float vals[8] = { va.x * rp, va.y * rp, va.z * rp, va.w * rp,
                      vb.x * rp, vb.y * rp, vb.z * rp, vb.w * rp };
    v8u hv, lv;
    #pragma unroll
    for (int j = 0; j < 8; ++j) {
      unsigned short h, lo2;
      f2hl(vals[j], h, lo2);
      hv[j] = h; lv[j] = lo2;
    }
    int slot = (bb * NSTEP + s) * 64 + l;
    Bhi[slot] = hv;
    Blo[slot] = lv;
  }
}

// ---------------- kernel B: att + K build via MFMA, c-split ----------------
// grid (128, 8), block 256 = 4 waves. Wave w: row-tile rt=w&1 (16 rows),
// c-half ch=w>>1 (512 c each). Total waves 4096 -> 4 blocks/CU = 16 waves/CU
// = 4 waves/SIMD (2x round 7, which sat latency-bound at 2/SIMD, attk~50us).
// Explicit 1-deep prefetch: loads for step s+1 issued before computing s, two
// register buffer sets, so vmcnt never drains in steady state. Partial acc+ss
// combined across the c-half pair via LDS; ch==0 waves do norm/exp/store.
__global__ __launch_bounds__(256, 4) void attk_kernel(
    const float* __restrict__ feat, const int* __restrict__ masks,
    const float* __restrict__ ws, float* __restrict__ Kmat) {
  int bb = blockIdx.y;
  int w = threadIdx.x >> 6, lane = threadIdx.x & 63;
  int rt = w & 1;                 // row-tile within block
  int ch = w >> 1;                // c-half
  int n0 = blockIdx.x * 32 + rt * 16;
  int rowa = lane & 15;           // A-frag row / B-frag col(proto)
  int quad = lane >> 4;           // k-chunk selector

  const v8s* Bhi = (const v8s*)(ws + WS_BHI)
                   + ((size_t)bb * NSTEP + ch * HSTEP) * 64 + lane;
  const v8s* Blo = (const v8s*)(ws + WS_BLO)
                   + ((size_t)bb * NSTEP + ch * HSTEP) * 64 + lane;
  const float* frow = feat + ((size_t)(bb * NUM + n0 + rowa)) * CDIM
                      + ch * 512 + quad * 4;

  v4f acc0 = {0.f, 0.f, 0.f, 0.f};
  v4f acc1 = {0.f, 0.f, 0.f, 0.f};
  float ss0 = 0.f, ss1 = 0.f;

  // prefetch step 0 into buffer set 0
  float4 va0 = *(const float4*)(frow);
  float4 vb0 = *(const float4*)(frow + 16);
  v8s bh0 = Bhi[0], bl0 = Blo[0];

  #pragma unroll 1
  for (int s2 = 0; s2 < HSTEP; s2 += 2) {
    // issue loads for step s2+1 (buffer set 1)
    int sn = s2 + 1;
    float4 va1 = *(const float4*)(frow + 32 * sn);
    float4 vb1 = *(const float4*)(frow + 32 * sn + 16);
    v8s bh1 = Bhi[sn * 64], bl1 = Blo[sn * 64];

    // compute step s2 from buffer set 0
    {
      float vals[8] = { va0.x, va0.y, va0.z, va0.w, vb0.x, vb0.y, vb0.z, vb0.w };
      v8s ah, al;
      #pragma unroll
      for (int j = 0; j < 8; ++j) {
        unsigned short h, lo2;
        f2hl(vals[j], h, lo2);
        ah[j] = (short)h; al[j] = (short)lo2;
        ss0 = fmaf(vals[j], vals[j], ss0);
      }
      acc0 = __builtin_amdgcn_mfma_f32_16x16x32_bf16(ah, bh0, acc0, 0, 0, 0);
      acc0 = __builtin_amdgcn_mfma_f32_16x16x32_bf16(al, bh0, acc0, 0, 0, 0);
      acc0 = __builtin_amdgcn_mfma_f32_16x16x32_bf16(ah, bl0, acc0, 0, 0, 0);
    }

    // issue loads for step s2+2 (buffer set 0; clamped dummy at tail)
    int sm = (s2 + 2 < HSTEP) ? s2 + 2 : 0;
    va0 = *(const float4*)(frow + 32 * sm);
    vb0 = *(const float4*)(frow + 32 * sm + 16);
    bh0 = Bhi[sm * 64]; bl0 = Blo[sm * 64];

    // compute step s2+1 from buffer set 1
    {
      float vals[8] = { va1.x, va1.y, va1.z, va1.w, vb1.x, vb1.y, vb1.z, vb1.w };
      v8s ah, al;
      #pragma unroll
      for (int j = 0; j < 8; ++j) {
        unsigned short h, lo2;
        f2hl(vals[j], h, lo2);
        ah[j] = (short)h; al[j] = (short)lo2;
        ss1 = fmaf(vals[j], vals[j], ss1);
      }
      acc1 = __builtin_amdgcn_mfma_f32_16x16x32_bf16(ah, bh1, acc1, 0, 0, 0);
      acc1 = __builtin_amdgcn_mfma_f32_16x16x32_bf16(al, bh1, acc1, 0, 0, 0);
      acc1 = __builtin_amdgcn_mfma_f32_16x16x32_bf16(ah, bl1, acc1, 0, 0, 0);
    }
  }

  v4f acc = acc0 + acc1;
  float ss = ss0 + ss1;

  // combine the two c-halves via LDS: [ch][rt][lane][acc0..3, ss]
  __shared__ float comb[2][2][64][5];
  comb[ch][rt][lane][0] = acc[0];
  comb[ch][rt][lane][1] = acc[1];
  comb[ch][rt][lane][2] = acc[2];
  comb[ch][rt][lane][3] = acc[3];
  comb[ch][rt][lane][4] = ss;
  __syncthreads();
  if (ch == 0) {
    acc[0] += comb[1][rt][lane][0];
    acc[1] += comb[1][rt][lane][1];
    acc[2] += comb[1][rt][lane][2];
    acc[3] += comb[1][rt][lane][3];
    ss     += comb[1][rt][lane][4];

    // full row norm for row (lane&15): lanes l, l^16, l^32, l^48 cover
    // disjoint c-quarters after the half-combine
    ss += __shfl_xor(ss, 16, 64);
    ss += __shfl_xor(ss, 32, 64);
    float rn = 1.0f / fmaxf(sqrtf(ss), FEPS);

    // C/D layout (m89-verified): col = lane&15 (proto), row = quad*4 + q
    float* Kb = Kmat + (size_t)bb * NUM * KSTR;
    #pragma unroll
    for (int q = 0; q < 4; ++q) {
      int r = quad * 4 + q;
      float rq = __shfl(rn, r, 64);         // lane r (<16) holds row r's norm
      float kv = __expf((acc[q] * rq - 1.0f) * 20.0f);  // exp(-(1-att)/0.05)
      Kb[(size_t)(n0 + r) * KSTR + rowa] = kv;
    }
    if (lane < 16) {
      int mv = masks[bb * NUM + n0 + lane];
      // exp(-2/0.05) = exp(-40), or exp(0)=1
      Kb[(size_t)(n0 + lane) * KSTR + 16] = (mv > 0) ? 4.248354255291589e-18f : 1.0f;
    }
  }
}

// ---------------- kernel C: Sinkhorn iterations + epilogue ----------------
// 8 blocks (one per batch) x 512 threads; thread owns rows t + 512*j.
// Inner loops packed as f32x2 + elementwise_fma -> v_pk_fma_f32. col = 1/4096
// folded out exactly: u' = 1/max(Kv,eps); v = (row*4096)/max(K^T u', eps*4096).
__global__ __launch_bounds__(512, 2) void sinkhorn_kernel(
    const float* __restrict__ Kmat, const float* __restrict__ numbg,
    float* __restrict__ out) {
  int bb = blockIdx.x;
  int t = threadIdx.x;
  const float* Kb = Kmat + (size_t)bb * NUM * KSTR;

  f32x2 kreg2[8][8];
  float k16[8];
  #pragma unroll
  for (int j = 0; j < 8; ++j) {
    int n = t + 512 * j;
    const float* kr = Kb + (size_t)n * KSTR;
    #pragma unroll
    for (int q = 0; q < 4; ++q) {
      float4 v = *(const float4*)(kr + 4 * q);
      kreg2[j][2*q+0] = f32x2{v.x, v.y};
      kreg2[j][2*q+1] = f32x2{v.z, v.w};
    }
    k16[j] = kr[16];
  }

  float nbg    = numbg[bb];
  // col-folded row constants (x4096)
  float rowp_c  = (4096.0f - nbg) * (1.0f / 16.0f);
  float row16_c = nbg;

  __shared__ float vlds[KC];
  __shared__ float part[KC][520];
  __shared__ int   flags[2];
  if (t < KC) vlds[t] = 1.0f;
  if (t == 0) { flags[0] = 0; flags[1] = 0; }
  __syncthreads();

  float u[8];
  #pragma unroll 1
  for (int it = 0; it < NITER; ++it) {
    f32x2 vr2[8];
    #pragma unroll
    for (int p = 0; p < 8; ++p) vr2[p] = f32x2{vlds[2*p], vlds[2*p+1]};
    float vr16 = vlds[16];

    f32x2 s2[8];
    #pragma unroll
    for (int p = 0; p < 8; ++p) s2[p] = f32x2{0.f, 0.f};
    float s16 = 0.f;

    #pragma unroll
    for (int j = 0; j < 8; ++j) {
      f32x2 d2 = kreg2[j][0] * vr2[0];
      #pragma unroll
      for (int p = 1; p < 8; ++p)
        d2 = __builtin_elementwise_fma(kreg2[j][p], vr2[p], d2);
      float dot = d2.x + d2.y + k16[j] * vr16;
      float uu = __builtin_amdgcn_rcpf(fmaxf(dot, FEPS));   // u' = 1/dot
      u[j] = uu;
      f32x2 uu2 = f32x2{uu, uu};
      #pragma unroll
      for (int p = 0; p < 8; ++p)
        s2[p] = __builtin_elementwise_fma(kreg2[j][p], uu2, s2[p]);
      s16 = fmaf(k16[j], uu, s16);
    }
    #pragma unroll
    for (int p = 0; p < 8; ++p) {
      part[2*p+0][t] = s2[p].x;
      part[2*p+1][t] = s2[p].y;
    }
    part[16][t] = s16;
    if (t == 0) flags[it & 1] = 0;
    __syncthreads();
    // stage 2: 17 groups x 16 threads sum 512 partials each
    if (t < 272) {
      int k = t >> 4, i = t & 15;
      float acc = 0.f;
      #pragma unroll
      for (int j = 0; j < 32; ++j) acc += part[k][i + 16 * j];
      acc += __shfl_xor(acc, 1, 64);
      acc += __shfl_xor(acc, 2, 64);
      acc += __shfl_xor(acc, 4, 64);
      acc += __shfl_xor(acc, 8, 64);
      if (i == 0) {
        float rw = (k < KP) ? rowp_c : row16_c;
        float vold = vlds[k];
        float vnew = rw * __builtin_amdgcn_rcpf(fmaxf(acc, FEPS2));
        vlds[k] = vnew;
        if (fabsf(vnew - vold) > 1e-6f * fabsf(vnew)) flags[it & 1] = 1;
      }
    }
    __syncthreads();
    if (flags[it & 1] == 0) break;   // converged: remaining ref iters are no-ops
  }

  // epilogue: T = u * K * v * 4096, relu, drop trash col; u[]*4096*col == u[]
  float vl[KP];
  #pragma unroll
  for (int p = 0; p < KP; ++p) vl[p] = vlds[p];
  float* ob = out + (size_t)bb * NUM * KP;
  #pragma unroll
  for (int j = 0; j < 8; ++j) {
    int n = t + 512 * j;
    float uu = u[j];
    float* dst = ob + (size_t)n * KP;
    #pragma unroll
    for (int q = 0; q < 4; ++q) {
      float4 v;
      v.x = fmaxf(uu * kreg2[j][2*q+0].x * vl[4*q+0], 0.f);
      v.y = fmaxf(uu * kreg2[j][2*q+0].y * vl[4*q+1], 0.f);
      v.z = fmaxf(uu * kreg2[j][2*q+1].x * vl[4*q+2], 0.f);
      v.w = fmaxf(uu * kreg2[j][2*q+1].y * vl[4*q+3], 0.f);
      *(float4*)(dst + 4 * q) = v;
    }
  }
}

extern "C" void kernel_launch(void* const* d_in, const int* in_sizes, int n_in,
                              void* d_out, int out_size, void* d_ws, size_t ws_size,
                              hipStream_t stream) {
  const float* feat   = (const float*)d_in[0];
  const float* protos = (const float*)d_in[1];
  const int*   masks  = (const int*)d_in[2];
  float* out = (float*)d_out;
  float* ws  = (float*)d_ws;

  float* Kmat  = ws + WS_K;
  float* numbg = ws + WS_NBG;

  hipLaunchKernelGGL(prep_kernel, dim3(NBATCH), dim3(256), 0, stream,
                     protos, masks, ws);
  hipLaunchKernelGGL(attk_kernel, dim3(128, NBATCH), dim3(256), 0, stream,
                     feat, masks, ws, Kmat);
  hipLaunchKernelGGL(sinkhorn_kernel, dim3(NBATCH), dim3(512), 0, stream,
                     Kmat, numbg, out);
}